// Round 1
// baseline (159.380 us; speedup 1.0000x reference)
//
#include <hip/hip_runtime.h>
#include <cstdint>

#define B_DIM 32
#define T_DIM 1024
#define NIN 128
#define NG 16       // i-groups of 8
#define NHID 1024
#define KSLOT 8
#define NWORDS 34   // 2 guard words (64 zero bits) + 32 data words
#define WAVES 16
#define CHUNKS 32
#define ROUNDS (CHUNKS / WAVES)
#define WSCALE 16.0f

// Per-k&3 conversion scales for the mask-ladder (masks 1/2/4/8 give 1x/2x/4x/-8x sums;
// nibble 0x8 is -8 as signed i4, folded into a negative scale). All exact powers of 2.
#define SC0 (1.0f / 16.0f)
#define SC1 (1.0f / 32.0f)
#define SC2 (1.0f / 64.0f)
#define SC3 (-1.0f / 128.0f)

// 8 x i4 MAC in one instruction (v_dot8_i32_i4). Fallback preserves semantics.
__device__ __forceinline__ int dot8acc(uint32_t sel, uint32_t wq, int acc) {
#if __has_builtin(__builtin_amdgcn_sdot8)
    return __builtin_amdgcn_sdot8((int)sel, (int)wq, acc, false);
#else
    #pragma unroll
    for (int m = 0; m < 8; ++m) {
        int s = ((int)((sel >> (4 * m)) & 0xF) << 28) >> 28;   // signed i4
        int q = ((int)((wq  >> (4 * m)) & 0xF) << 28) >> 28;   // signed i4
        acc += s * q;
    }
    return acc;
#endif
}

__device__ __forceinline__ uint32_t permb(uint32_t hi, uint32_t lo, uint32_t sel) {
#if __has_builtin(__builtin_amdgcn_perm)
    return __builtin_amdgcn_perm(hi, lo, sel);   // S0=hi(bytes 7..4), S1=lo(bytes 3..0)
#else
    union { uint32_t w[2]; unsigned char b[8]; } src;
    src.w[0] = lo; src.w[1] = hi;
    uint32_t r = 0;
    for (int n = 0; n < 4; ++n) r |= (uint32_t)src.b[(sel >> (8 * n)) & 7] << (8 * n);
    return r;
#endif
}

__device__ __forceinline__ uint32_t funnel32(uint32_t hi, uint32_t lo, uint32_t sh) {
#if __has_builtin(__builtin_amdgcn_alignbit)
    return __builtin_amdgcn_alignbit(hi, lo, sh);   // ((hi:lo) >> (sh&31)) low 32
#else
    return (uint32_t)(((((uint64_t)hi) << 32) | lo) >> (sh & 31));
#endif
}

// window for one stream: pick word pair by (sp>=32), funnel by sp&31
__device__ __forceinline__ uint32_t mkwin(uint32_t sp, uint32_t wa, uint32_t wb, uint32_t wc) {
    uint32_t lo = (sp >= 32u) ? wb : wa;
    uint32_t hi = (sp >= 32u) ? wc : wb;
    return funnel32(hi, lo, sp);
}

// ---------------- merged prep kernel ----------------
// blocks   0..511: pack spike bits TRANSPOSED: xbitsT[b][w][i]
// blocks 512..575: packed per-(g,h) params: {sp bytes lo, sp bytes hi, wq nibbles, pad}
//                  (sp = 63 - delay; wq nibble order [0,4,1,5,2,6,3,7])
// blocks 576..580: init out (logits = bias, totals = 0)
__global__ void prep_kernel(const float* __restrict__ x, const float* __restrict__ W,
                            const float* __restrict__ draw, const float* __restrict__ b_ro,
                            uint32_t* __restrict__ xbitsT, uint4* __restrict__ pk4,
                            float* __restrict__ out) {
    int blk = blockIdx.x, tid = threadIdx.x;
    if (blk < 512) {
        int idx = blk * 256 + tid;        // 131072 = b*4096 + w*128 + i
        int b = idx >> 12, w = (idx >> 7) & 31, i = idx & 127;
        const float* xp = x + (size_t)b * T_DIM * NIN + (size_t)w * 32 * NIN + i;
        uint32_t word = 0;
        #pragma unroll
        for (int bit = 0; bit < 32; ++bit) {
            float xv = xp[(size_t)bit * NIN];   // lanes = consecutive i -> coalesced
            word |= (xv != 0.0f) ? (1u << bit) : 0u;
        }
        uint32_t* bp = xbitsT + (size_t)b * NWORDS * NIN;
        bp[(2 + w) * NIN + i] = word;           // transposed: [w][i]
        if (w == 0) { bp[i] = 0u; bp[NIN + i] = 0u; }   // guard rows
    } else if (blk < 576) {
        int idx = (blk - 512) * 256 + tid;    // 16384 = g*1024 + h
        int g = idx >> 10, h = idx & 1023;
        const float* Wp = W    + (size_t)h * NIN + 8 * g;
        const float* Rp = draw + (size_t)h * NIN + 8 * g;
        uint32_t s0 = 0, s1 = 0, wq = 0;
        const int ordm[8] = {0, 4, 1, 5, 2, 6, 3, 7};
        #pragma unroll
        for (int j = 0; j < 4; ++j) {
            int sp_a = 63 - (int)rintf(50.0f / (1.0f + expf(-Rp[j])));      // RNE = jnp.round
            int sp_b = 63 - (int)rintf(50.0f / (1.0f + expf(-Rp[4 + j])));
            s0 |= (uint32_t)sp_a << (8 * j);
            s1 |= (uint32_t)sp_b << (8 * j);
        }
        #pragma unroll
        for (int m = 0; m < 8; ++m) {
            int q = (int)rintf(fminf(fmaxf(Wp[ordm[m]] * WSCALE, -8.0f), 7.0f));
            wq |= ((uint32_t)q & 0xFu) << (4 * m);
        }
        pk4[(size_t)g * NHID + h] = make_uint4(s0, s1, wq, 0u);
    } else {
        int idx = (blk - 576) * 256 + tid;    // 1280 outputs
        if (idx < B_DIM * KSLOT) out[idx] = b_ro[0];
        else if (idx < B_DIM * KSLOT + T_DIM) out[idx] = 0.0f;
    }
}

// ---------------- fused sdot8 mask-ladder + wave-relay LIF ----------------
// block = (b, hg of 64 h), 1024 threads = 16 waves, grid 512.
// R14 = R13 with 16 waves/block (ROUNDS 2): grid 512 caps the chip at 2 blocks/CU,
// so 8-wave blocks left 16/32 wave slots empty (Occupancy 31%, VALUBusy 75%) —
// relay-wait idle with nothing to fill it. Same per-chunk work, same LDS (36.9 KB,
// 2 blocks/CU = 74 KB), same relay protocol; each wave owns 2 chunks instead of 4.
// VGPR=36 <= 64 admits 8 waves/SIMD, declared via launch_bounds(1024, 8).
// R12 lesson: NO software pipelining — double-buffered staging spilled acc[] to
// scratch (WRITE_SIZE 128 KB -> 1.9 GB, 20x regression). With acc[32] resident,
// register headroom under launch_bounds admits no extra prefetch set.
__global__ __launch_bounds__(1024, 8) void fused_kernel(
    const uint4* __restrict__ pk4, const uint32_t* __restrict__ xbitsT,
    float* __restrict__ out, const float* __restrict__ w_ro,
    const int* __restrict__ ss, const int* __restrict__ se) {
    __shared__ uint32_t lds_x[NWORDS * NIN];  // [w][i]   17 KB (transposed)
    __shared__ uint4    lds_pk[NG * 64];      // [g][hl]  16 KB {sp lo, sp hi, wq, pad}
    __shared__ float st_v[64];
    __shared__ float st_rf[64];
    __shared__ float st_sacc[KSLOT][64];      // authoritative (lazy relay)
    __shared__ int   flag;

    int bx = blockIdx.x;
    int hg = bx & 15;
    int b  = bx >> 4;
    int tid  = threadIdx.x;
    int lane = tid & 63;
    int sub  = tid >> 6;
    int hbase = hg * 64;

    for (int idx = tid; idx < NWORDS * NIN; idx += 1024)
        lds_x[idx] = xbitsT[(size_t)b * NWORDS * NIN + idx];
    for (int idx = tid; idx < NG * 64; idx += 1024) {
        int g = idx >> 6, hl = idx & 63;
        lds_pk[idx] = pk4[(size_t)g * NHID + hbase + hl];
    }
    if (tid < 64) { st_v[tid] = 0.0f; st_rf[tid] = 0.0f; }
    if (tid < KSLOT * 64) ((float*)st_sacc)[tid] = 0.0f;
    if (tid == 0) flag = 0;
    __syncthreads();

    int st_[KSLOT], en_[KSLOT];
    #pragma unroll
    for (int k = 0; k < KSLOT; ++k) {
        st_[k] = __builtin_amdgcn_readfirstlane(ss[k]);
        en_[k] = __builtin_amdgcn_readfirstlane(se[k]);
    }

    for (int rl = 0; rl < ROUNDS; ++rl) {
        int c  = __builtin_amdgcn_readfirstlane(rl * WAVES + sub);
        int t0 = c * 32;
        int acc[32];
        #pragma unroll
        for (int k = 0; k < 32; ++k) acc[k] = 0;
        const uint32_t* xrow = lds_x + c * NIN;   // per-chunk base; offsets immediate
        #pragma unroll 2
        for (int g = 0; g < NG; ++g) {
            uint4 pkc = lds_pk[(g << 6) | lane];  // one ds_read_b128: {sp lo, sp hi, wq}
            uint32_t wq = pkc.z;
            uint32_t win[8];
            {   // half 0: streams 8g..8g+3 — 3 uniform b128; consume fields directly
                uint4 a  = *(const uint4*)(xrow + 8 * g);
                uint4 bq = *(const uint4*)(xrow + NIN + 8 * g);
                uint4 cq = *(const uint4*)(xrow + 2 * NIN + 8 * g);
                win[0] = mkwin(pkc.x & 0xFFu,         a.x, bq.x, cq.x);
                win[1] = mkwin((pkc.x >> 8) & 0xFFu,  a.y, bq.y, cq.y);
                win[2] = mkwin((pkc.x >> 16) & 0xFFu, a.z, bq.z, cq.z);
                win[3] = mkwin(pkc.x >> 24,           a.w, bq.w, cq.w);
            }
            {   // half 1: streams 8g+4..8g+7
                uint4 a  = *(const uint4*)(xrow + 8 * g + 4);
                uint4 bq = *(const uint4*)(xrow + NIN + 8 * g + 4);
                uint4 cq = *(const uint4*)(xrow + 2 * NIN + 8 * g + 4);
                win[4] = mkwin(pkc.y & 0xFFu,         a.x, bq.x, cq.x);
                win[5] = mkwin((pkc.y >> 8) & 0xFFu,  a.y, bq.y, cq.y);
                win[6] = mkwin((pkc.y >> 16) & 0xFFu, a.z, bq.z, cq.z);
                win[7] = mkwin(pkc.y >> 24,           a.w, bq.w, cq.w);
            }
            // ---- byte-interleave; X nibble order [s0,s4,s1,s5,s2,s6,s3,s7] = wq packing ----
            uint32_t A0 = permb(win[1], win[0], 0x05010400u);
            uint32_t B0 = permb(win[1], win[0], 0x07030602u);
            uint32_t C0 = permb(win[3], win[2], 0x05010400u);
            uint32_t D0 = permb(win[3], win[2], 0x07030602u);
            uint32_t A1 = permb(win[5], win[4], 0x05010400u);
            uint32_t B1 = permb(win[5], win[4], 0x07030602u);
            uint32_t C1 = permb(win[7], win[6], 0x05010400u);
            uint32_t D1 = permb(win[7], win[6], 0x07030602u);
            {
                uint32_t P = permb(C0, A0, 0x05040100u);
                uint32_t Q = permb(C1, A1, 0x05040100u);
                uint32_t X0 = (P & 0x0F0F0F0Fu) | ((Q << 4) & 0xF0F0F0F0u);
                uint32_t X1 = ((P >> 4) & 0x0F0F0F0Fu) | (Q & 0xF0F0F0F0u);
                acc[0] = dot8acc(X0 & 0x11111111u, wq, acc[0]);   // 1x
                acc[1] = dot8acc(X0 & 0x22222222u, wq, acc[1]);   // 2x
                acc[2] = dot8acc(X0 & 0x44444444u, wq, acc[2]);   // 4x
                acc[3] = dot8acc(X0 & 0x88888888u, wq, acc[3]);   // -8x
                acc[4] = dot8acc(X1 & 0x11111111u, wq, acc[4]);
                acc[5] = dot8acc(X1 & 0x22222222u, wq, acc[5]);
                acc[6] = dot8acc(X1 & 0x44444444u, wq, acc[6]);
                acc[7] = dot8acc(X1 & 0x88888888u, wq, acc[7]);
            }
            {
                uint32_t P = permb(C0, A0, 0x07060302u);
                uint32_t Q = permb(C1, A1, 0x07060302u);
                uint32_t X2 = (P & 0x0F0F0F0Fu) | ((Q << 4) & 0xF0F0F0F0u);
                uint32_t X3 = ((P >> 4) & 0x0F0F0F0Fu) | (Q & 0xF0F0F0F0u);
                acc[8]  = dot8acc(X2 & 0x11111111u, wq, acc[8]);
                acc[9]  = dot8acc(X2 & 0x22222222u, wq, acc[9]);
                acc[10] = dot8acc(X2 & 0x44444444u, wq, acc[10]);
                acc[11] = dot8acc(X2 & 0x88888888u, wq, acc[11]);
                acc[12] = dot8acc(X3 & 0x11111111u, wq, acc[12]);
                acc[13] = dot8acc(X3 & 0x22222222u, wq, acc[13]);
                acc[14] = dot8acc(X3 & 0x44444444u, wq, acc[14]);
                acc[15] = dot8acc(X3 & 0x88888888u, wq, acc[15]);
            }
            {
                uint32_t P = permb(D0, B0, 0x05040100u);
                uint32_t Q = permb(D1, B1, 0x05040100u);
                uint32_t X4 = (P & 0x0F0F0F0Fu) | ((Q << 4) & 0xF0F0F0F0u);
                uint32_t X5 = ((P >> 4) & 0x0F0F0F0Fu) | (Q & 0xF0F0F0F0u);
                acc[16] = dot8acc(X4 & 0x11111111u, wq, acc[16]);
                acc[17] = dot8acc(X4 & 0x22222222u, wq, acc[17]);
                acc[18] = dot8acc(X4 & 0x44444444u, wq, acc[18]);
                acc[19] = dot8acc(X4 & 0x88888888u, wq, acc[19]);
                acc[20] = dot8acc(X5 & 0x11111111u, wq, acc[20]);
                acc[21] = dot8acc(X5 & 0x22222222u, wq, acc[21]);
                acc[22] = dot8acc(X5 & 0x44444444u, wq, acc[22]);
                acc[23] = dot8acc(X5 & 0x88888888u, wq, acc[23]);
            }
            {
                uint32_t P = permb(D0, B0, 0x07060302u);
                uint32_t Q = permb(D1, B1, 0x07060302u);
                uint32_t X6 = (P & 0x0F0F0F0Fu) | ((Q << 4) & 0xF0F0F0F0u);
                uint32_t X7 = ((P >> 4) & 0x0F0F0F0Fu) | (Q & 0xF0F0F0F0u);
                acc[24] = dot8acc(X6 & 0x11111111u, wq, acc[24]);
                acc[25] = dot8acc(X6 & 0x22222222u, wq, acc[25]);
                acc[26] = dot8acc(X6 & 0x44444444u, wq, acc[26]);
                acc[27] = dot8acc(X6 & 0x88888888u, wq, acc[27]);
                acc[28] = dot8acc(X7 & 0x11111111u, wq, acc[28]);
                acc[29] = dot8acc(X7 & 0x22222222u, wq, acc[29]);
                acc[30] = dot8acc(X7 & 0x44444444u, wq, acc[30]);
                acc[31] = dot8acc(X7 & 0x88888888u, wq, acc[31]);
            }
        }
        // ---- relay: wait for token ----
        while (__builtin_amdgcn_readfirstlane(*(volatile int*)&flag) != c)
            __builtin_amdgcn_s_sleep(1);
        float v  = st_v[lane];
        float rf = st_rf[lane];
        // ---- LIF fast path (exact detection of slow-path need) ----
        float vf = v, vmax = -1.0f;
        #pragma unroll
        for (int k = 0; k < 32; ++k) {
            float sc = ((k & 3) == 0) ? SC0 : ((k & 3) == 1) ? SC1 : ((k & 3) == 2) ? SC2 : SC3;
            float I = (float)acc[k] * sc;
            vf = vf + 0.1f * (I - vf);
            vmax = fmaxf(vmax, vf);
        }
        bool slow = (rf > 0.0f) || (vmax >= 1.0f);
        if (__ballot(slow) != 0ULL) {
            // ---- exact path (rare: >=7 sigma margin) ----
            float sacc[KSLOT];
            #pragma unroll
            for (int k = 0; k < KSLOT; ++k) sacc[k] = st_sacc[k][lane];
            #pragma unroll
            for (int k = 0; k < 32; ++k) {
                float sc = ((k & 3) == 0) ? SC0 : ((k & 3) == 1) ? SC1 : ((k & 3) == 2) ? SC2 : SC3;
                float I = (float)acc[k] * sc;
                int t = t0 + k;
                bool active = (rf <= 0.0f);
                float vupd = v + 0.1f * (I - v);
                float vn = active ? vupd : v;
                bool spike = active && (vn >= 1.0f);
                unsigned long long bal = __ballot(spike);
                if (bal != 0ULL) {
                    if (spike) {
                        vn = 0.0f;                // V_RESET
                        #pragma unroll
                        for (int k2 = 0; k2 < KSLOT; ++k2)
                            if (t >= st_[k2] && t < en_[k2]) sacc[k2] += 1.0f;
                    }
                    rf = spike ? 2.0f : fmaxf(rf - 1.0f, 0.0f);
                    if (lane == 0) atomicAdd(&out[B_DIM * KSLOT + t], (float)__popcll(bal));
                } else {
                    rf = fmaxf(rf - 1.0f, 0.0f);
                }
                v = vn;
            }
            #pragma unroll
            for (int k = 0; k < KSLOT; ++k) st_sacc[k][lane] = sacc[k];
        } else {
            v = vf;
            rf = 0.0f;
        }
        st_v[lane]  = v;
        st_rf[lane] = rf;
        __threadfence_block();                     // drain LDS writes before flag release
        if (lane == 0) *(volatile int*)&flag = c + 1;
    }
    // ---- epilogue: after chunk 31's relay write, LDS sacc is final ----
    if (sub == WAVES - 1) {
        float wr = w_ro[hbase + lane];
        #pragma unroll
        for (int k = 0; k < KSLOT; ++k) {
            float val = st_sacc[k][lane] * wr;
            #pragma unroll
            for (int o = 32; o > 0; o >>= 1) val += __shfl_down(val, o);
            if (lane == 0) atomicAdd(&out[b * KSLOT + k], val);
        }
    }
}

extern "C" void kernel_launch(void* const* d_in, const int* in_sizes, int n_in,
                              void* d_out, int out_size, void* d_ws, size_t ws_size,
                              hipStream_t stream) {
    const float* x   = (const float*)d_in[0];
    const float* W   = (const float*)d_in[1];
    const float* drw = (const float*)d_in[2];
    const float* wro = (const float*)d_in[3];
    const float* bro = (const float*)d_in[4];
    const int*   ss  = (const int*)d_in[5];
    const int*   se  = (const int*)d_in[6];
    float* out = (float*)d_out;

    uintptr_t base = (uintptr_t)d_ws;
    size_t off = 0;
    auto take = [&](size_t bytes) {
        size_t o = off;
        off = (off + bytes + 255) & ~(size_t)255;
        return (void*)(base + o);
    };
    uint32_t* xbitsT = (uint32_t*)take((size_t)B_DIM * NWORDS * NIN * 4);
    uint4*    pk4    = (uint4*)take((size_t)NG * NHID * 16);
    (void)ws_size;

    prep_kernel<<<581, 256, 0, stream>>>(x, W, drw, bro, xbitsT, pk4, out);
    fused_kernel<<<512, 1024, 0, stream>>>(pk4, xbitsT, out, wro, ss, se);
}

// Round 2
// 151.518 us; speedup vs baseline: 1.0519x; 1.0519x over previous
//
#include <hip/hip_runtime.h>
#include <cstdint>

#define B_DIM 32
#define T_DIM 1024
#define NIN 128
#define NG 16       // i-groups of 8
#define NHID 1024
#define KSLOT 8
#define NWORDS 34   // 2 guard words (64 zero bits) + 32 data words
#define WAVES 8
#define CHUNKS 32
#define PAIRS (CHUNKS / 2)
#define ROUNDS (PAIRS / WAVES)
#define WSCALE 16.0f

// Per-k&3 conversion scales for the mask-ladder (masks 1/2/4/8 give 1x/2x/4x/-8x sums;
// nibble 0x8 is -8 as signed i4, folded into a negative scale). All exact powers of 2.
#define SC0 (1.0f / 16.0f)
#define SC1 (1.0f / 32.0f)
#define SC2 (1.0f / 64.0f)
#define SC3 (-1.0f / 128.0f)

// 8 x i4 MAC in one instruction (v_dot8_i32_i4). Fallback preserves semantics.
__device__ __forceinline__ int dot8acc(uint32_t sel, uint32_t wq, int acc) {
#if __has_builtin(__builtin_amdgcn_sdot8)
    return __builtin_amdgcn_sdot8((int)sel, (int)wq, acc, false);
#else
    #pragma unroll
    for (int m = 0; m < 8; ++m) {
        int s = ((int)((sel >> (4 * m)) & 0xF) << 28) >> 28;   // signed i4
        int q = ((int)((wq  >> (4 * m)) & 0xF) << 28) >> 28;   // signed i4
        acc += s * q;
    }
    return acc;
#endif
}

__device__ __forceinline__ uint32_t permb(uint32_t hi, uint32_t lo, uint32_t sel) {
#if __has_builtin(__builtin_amdgcn_perm)
    return __builtin_amdgcn_perm(hi, lo, sel);   // S0=hi(bytes 7..4), S1=lo(bytes 3..0)
#else
    union { uint32_t w[2]; unsigned char b[8]; } src;
    src.w[0] = lo; src.w[1] = hi;
    uint32_t r = 0;
    for (int n = 0; n < 4; ++n) r |= (uint32_t)src.b[(sel >> (8 * n)) & 7] << (8 * n);
    return r;
#endif
}

__device__ __forceinline__ uint32_t funnel32(uint32_t hi, uint32_t lo, uint32_t sh) {
#if __has_builtin(__builtin_amdgcn_alignbit)
    return __builtin_amdgcn_alignbit(hi, lo, sh);   // ((hi:lo) >> (sh&31)) low 32
#else
    return (uint32_t)(((((uint64_t)hi) << 32) | lo) >> (sh & 31));
#endif
}

// ---------------- merged prep kernel ----------------
// blocks   0..511: pack spike bits TRANSPOSED: xbitsT[b][w][i]
// blocks 512..575: packed per-(g,h) params: {sp bytes lo, sp bytes hi, wq nibbles, pad}
//                  (sp = 63 - delay; wq nibble order [0,4,1,5,2,6,3,7])
// blocks 576..580: init out (logits = bias, totals = 0)
__global__ void prep_kernel(const float* __restrict__ x, const float* __restrict__ W,
                            const float* __restrict__ draw, const float* __restrict__ b_ro,
                            uint32_t* __restrict__ xbitsT, uint4* __restrict__ pk4,
                            float* __restrict__ out) {
    int blk = blockIdx.x, tid = threadIdx.x;
    if (blk < 512) {
        int idx = blk * 256 + tid;        // 131072 = b*4096 + w*128 + i
        int b = idx >> 12, w = (idx >> 7) & 31, i = idx & 127;
        const float* xp = x + (size_t)b * T_DIM * NIN + (size_t)w * 32 * NIN + i;
        uint32_t word = 0;
        #pragma unroll
        for (int bit = 0; bit < 32; ++bit) {
            float xv = xp[(size_t)bit * NIN];   // lanes = consecutive i -> coalesced
            word |= (xv != 0.0f) ? (1u << bit) : 0u;
        }
        uint32_t* bp = xbitsT + (size_t)b * NWORDS * NIN;
        bp[(2 + w) * NIN + i] = word;           // transposed: [w][i]
        if (w == 0) { bp[i] = 0u; bp[NIN + i] = 0u; }   // guard rows
    } else if (blk < 576) {
        int idx = (blk - 512) * 256 + tid;    // 16384 = g*1024 + h
        int g = idx >> 10, h = idx & 1023;
        const float* Wp = W    + (size_t)h * NIN + 8 * g;
        const float* Rp = draw + (size_t)h * NIN + 8 * g;
        uint32_t s0 = 0, s1 = 0, wq = 0;
        const int ordm[8] = {0, 4, 1, 5, 2, 6, 3, 7};
        #pragma unroll
        for (int j = 0; j < 4; ++j) {
            int sp_a = 63 - (int)rintf(50.0f / (1.0f + expf(-Rp[j])));      // RNE = jnp.round
            int sp_b = 63 - (int)rintf(50.0f / (1.0f + expf(-Rp[4 + j])));
            s0 |= (uint32_t)sp_a << (8 * j);
            s1 |= (uint32_t)sp_b << (8 * j);
        }
        #pragma unroll
        for (int m = 0; m < 8; ++m) {
            int q = (int)rintf(fminf(fmaxf(Wp[ordm[m]] * WSCALE, -8.0f), 7.0f));
            wq |= ((uint32_t)q & 0xFu) << (4 * m);
        }
        pk4[(size_t)g * NHID + h] = make_uint4(s0, s1, wq, 0u);
    } else {
        int idx = (blk - 576) * 256 + tid;    // 1280 outputs
        if (idx < B_DIM * KSLOT) out[idx] = b_ro[0];
        else if (idx < B_DIM * KSLOT + T_DIM) out[idx] = 0.0f;
    }
}

// mask-ladder: 8 windows (one 32-t word per stream) -> 32 per-t dots via sdot8.
// W_: uint32_t[8] windows; ACC: int[32]; WQ: packed weight nibbles.
#define LADDER(W_, ACC, WQ)                                                     \
    {                                                                           \
        uint32_t A0 = permb(W_[1], W_[0], 0x05010400u);                         \
        uint32_t B0 = permb(W_[1], W_[0], 0x07030602u);                         \
        uint32_t C0 = permb(W_[3], W_[2], 0x05010400u);                         \
        uint32_t D0 = permb(W_[3], W_[2], 0x07030602u);                         \
        uint32_t A1 = permb(W_[5], W_[4], 0x05010400u);                         \
        uint32_t B1 = permb(W_[5], W_[4], 0x07030602u);                         \
        uint32_t C1 = permb(W_[7], W_[6], 0x05010400u);                         \
        uint32_t D1 = permb(W_[7], W_[6], 0x07030602u);                         \
        {                                                                       \
            uint32_t P = permb(C0, A0, 0x05040100u);                            \
            uint32_t Q = permb(C1, A1, 0x05040100u);                            \
            uint32_t X0 = (P & 0x0F0F0F0Fu) | ((Q << 4) & 0xF0F0F0F0u);         \
            uint32_t X1 = ((P >> 4) & 0x0F0F0F0Fu) | (Q & 0xF0F0F0F0u);         \
            ACC[0] = dot8acc(X0 & 0x11111111u, WQ, ACC[0]);                     \
            ACC[1] = dot8acc(X0 & 0x22222222u, WQ, ACC[1]);                     \
            ACC[2] = dot8acc(X0 & 0x44444444u, WQ, ACC[2]);                     \
            ACC[3] = dot8acc(X0 & 0x88888888u, WQ, ACC[3]);                     \
            ACC[4] = dot8acc(X1 & 0x11111111u, WQ, ACC[4]);                     \
            ACC[5] = dot8acc(X1 & 0x22222222u, WQ, ACC[5]);                     \
            ACC[6] = dot8acc(X1 & 0x44444444u, WQ, ACC[6]);                     \
            ACC[7] = dot8acc(X1 & 0x88888888u, WQ, ACC[7]);                     \
        }                                                                       \
        {                                                                       \
            uint32_t P = permb(C0, A0, 0x07060302u);                            \
            uint32_t Q = permb(C1, A1, 0x07060302u);                            \
            uint32_t X2 = (P & 0x0F0F0F0Fu) | ((Q << 4) & 0xF0F0F0F0u);         \
            uint32_t X3 = ((P >> 4) & 0x0F0F0F0Fu) | (Q & 0xF0F0F0F0u);         \
            ACC[8]  = dot8acc(X2 & 0x11111111u, WQ, ACC[8]);                    \
            ACC[9]  = dot8acc(X2 & 0x22222222u, WQ, ACC[9]);                    \
            ACC[10] = dot8acc(X2 & 0x44444444u, WQ, ACC[10]);                   \
            ACC[11] = dot8acc(X2 & 0x88888888u, WQ, ACC[11]);                   \
            ACC[12] = dot8acc(X3 & 0x11111111u, WQ, ACC[12]);                   \
            ACC[13] = dot8acc(X3 & 0x22222222u, WQ, ACC[13]);                   \
            ACC[14] = dot8acc(X3 & 0x44444444u, WQ, ACC[14]);                   \
            ACC[15] = dot8acc(X3 & 0x88888888u, WQ, ACC[15]);                   \
        }                                                                       \
        {                                                                       \
            uint32_t P = permb(D0, B0, 0x05040100u);                            \
            uint32_t Q = permb(D1, B1, 0x05040100u);                            \
            uint32_t X4 = (P & 0x0F0F0F0Fu) | ((Q << 4) & 0xF0F0F0F0u);         \
            uint32_t X5 = ((P >> 4) & 0x0F0F0F0Fu) | (Q & 0xF0F0F0F0u);         \
            ACC[16] = dot8acc(X4 & 0x11111111u, WQ, ACC[16]);                   \
            ACC[17] = dot8acc(X4 & 0x22222222u, WQ, ACC[17]);                   \
            ACC[18] = dot8acc(X4 & 0x44444444u, WQ, ACC[18]);                   \
            ACC[19] = dot8acc(X4 & 0x88888888u, WQ, ACC[19]);                   \
            ACC[20] = dot8acc(X5 & 0x11111111u, WQ, ACC[20]);                   \
            ACC[21] = dot8acc(X5 & 0x22222222u, WQ, ACC[21]);                   \
            ACC[22] = dot8acc(X5 & 0x44444444u, WQ, ACC[22]);                   \
            ACC[23] = dot8acc(X5 & 0x88888888u, WQ, ACC[23]);                   \
        }                                                                       \
        {                                                                       \
            uint32_t P = permb(D0, B0, 0x07060302u);                            \
            uint32_t Q = permb(D1, B1, 0x07060302u);                            \
            uint32_t X6 = (P & 0x0F0F0F0Fu) | ((Q << 4) & 0xF0F0F0F0u);         \
            uint32_t X7 = ((P >> 4) & 0x0F0F0F0Fu) | (Q & 0xF0F0F0F0u);         \
            ACC[24] = dot8acc(X6 & 0x11111111u, WQ, ACC[24]);                   \
            ACC[25] = dot8acc(X6 & 0x22222222u, WQ, ACC[25]);                   \
            ACC[26] = dot8acc(X6 & 0x44444444u, WQ, ACC[26]);                   \
            ACC[27] = dot8acc(X6 & 0x88888888u, WQ, ACC[27]);                   \
            ACC[28] = dot8acc(X7 & 0x11111111u, WQ, ACC[28]);                   \
            ACC[29] = dot8acc(X7 & 0x22222222u, WQ, ACC[29]);                   \
            ACC[30] = dot8acc(X7 & 0x44444444u, WQ, ACC[30]);                   \
            ACC[31] = dot8acc(X7 & 0x88888888u, WQ, ACC[31]);                   \
        }                                                                       \
    }

// ---------------- fused sdot8 mask-ladder + wave-relay LIF ----------------
// block = (b, hg of 64 h), 512 threads = 8 waves, grid 512.
// R15 = R13 (8 waves, 88.5 us) + 2-chunk fusion: each wave computes a PAIR of
// consecutive 32-t chunks per round. Rationale (R14 post-mortem): occupancy 2x
// gave zero VALUBusy gain -> issue-bound; the lever is instruction count.
// Fusion shares per-g work across the pair: pk read 2->1, row reads 12->8 b128
// (rows c..c+3 serve both windows), sp extract/cmp/word-select shared
// (7 ops/stream for 2 windows vs 10). Relay handoffs halved (16 tokens).
// R12/R14 lesson: acc[] must stay in registers. accL[32]+accH[32]+win 16+rows 16
// ~= 110 VGPR peak under launch_bounds(512,4) cap of 128. Watch WRITE_SIZE:
// >1 MB means spill -> revert.
__global__ __launch_bounds__(512, 4) void fused_kernel(
    const uint4* __restrict__ pk4, const uint32_t* __restrict__ xbitsT,
    float* __restrict__ out, const float* __restrict__ w_ro,
    const int* __restrict__ ss, const int* __restrict__ se) {
    __shared__ uint32_t lds_x[NWORDS * NIN];  // [w][i]   17 KB (transposed)
    __shared__ uint4    lds_pk[NG * 64];      // [g][hl]  16 KB {sp lo, sp hi, wq, pad}
    __shared__ float st_v[64];
    __shared__ float st_rf[64];
    __shared__ float st_sacc[KSLOT][64];      // authoritative (lazy relay)
    __shared__ int   flag;

    int bx = blockIdx.x;
    int hg = bx & 15;
    int b  = bx >> 4;
    int tid  = threadIdx.x;
    int lane = tid & 63;
    int sub  = tid >> 6;
    int hbase = hg * 64;

    for (int idx = tid; idx < NWORDS * NIN; idx += 512)
        lds_x[idx] = xbitsT[(size_t)b * NWORDS * NIN + idx];
    for (int idx = tid; idx < NG * 64; idx += 512) {
        int g = idx >> 6, hl = idx & 63;
        lds_pk[idx] = pk4[(size_t)g * NHID + hbase + hl];
    }
    if (tid < 64) { st_v[tid] = 0.0f; st_rf[tid] = 0.0f; }
    if (tid < KSLOT * 64) ((float*)st_sacc)[tid] = 0.0f;
    if (tid == 0) flag = 0;
    __syncthreads();

    int st_[KSLOT], en_[KSLOT];
    #pragma unroll
    for (int k = 0; k < KSLOT; ++k) {
        st_[k] = __builtin_amdgcn_readfirstlane(ss[k]);
        en_[k] = __builtin_amdgcn_readfirstlane(se[k]);
    }

    for (int rl = 0; rl < ROUNDS; ++rl) {
        int p  = __builtin_amdgcn_readfirstlane(rl * WAVES + sub);   // pair index 0..15
        int t0 = p * 64;
        int accL[32], accH[32];
        #pragma unroll
        for (int k = 0; k < 32; ++k) { accL[k] = 0; accH[k] = 0; }
        const uint32_t* xrow = lds_x + (2 * p) * NIN;   // rows 2p .. 2p+3 used
        #pragma unroll 1
        for (int g = 0; g < NG; ++g) {
            uint4 pkc = lds_pk[(g << 6) | lane];  // one ds_read_b128: {sp lo, sp hi, wq}
            uint32_t wq = pkc.z;
            uint32_t wl[8], wh[8];
            {   // half 0: streams 8g..8g+3 — 4 uniform b128 rows serve BOTH chunks
                uint4 r0 = *(const uint4*)(xrow + 8 * g);
                uint4 r1 = *(const uint4*)(xrow + NIN + 8 * g);
                uint4 r2 = *(const uint4*)(xrow + 2 * NIN + 8 * g);
                uint4 r3 = *(const uint4*)(xrow + 3 * NIN + 8 * g);
                #pragma unroll
                for (int j = 0; j < 4; ++j) {
                    uint32_t sp = (pkc.x >> (8 * j)) & 0xFFu;
                    uint32_t w0 = j == 0 ? r0.x : j == 1 ? r0.y : j == 2 ? r0.z : r0.w;
                    uint32_t w1 = j == 0 ? r1.x : j == 1 ? r1.y : j == 2 ? r1.z : r1.w;
                    uint32_t w2 = j == 0 ? r2.x : j == 1 ? r2.y : j == 2 ? r2.z : r2.w;
                    uint32_t w3 = j == 0 ? r3.x : j == 1 ? r3.y : j == 2 ? r3.z : r3.w;
                    bool sel = sp >= 32u;
                    uint32_t a  = sel ? w1 : w0;
                    uint32_t bm = sel ? w2 : w1;
                    uint32_t b2 = sel ? w3 : w2;
                    wl[j] = funnel32(bm, a, sp);
                    wh[j] = funnel32(b2, bm, sp);
                }
            }
            {   // half 1: streams 8g+4..8g+7
                uint4 r0 = *(const uint4*)(xrow + 8 * g + 4);
                uint4 r1 = *(const uint4*)(xrow + NIN + 8 * g + 4);
                uint4 r2 = *(const uint4*)(xrow + 2 * NIN + 8 * g + 4);
                uint4 r3 = *(const uint4*)(xrow + 3 * NIN + 8 * g + 4);
                #pragma unroll
                for (int j = 0; j < 4; ++j) {
                    uint32_t sp = (pkc.y >> (8 * j)) & 0xFFu;
                    uint32_t w0 = j == 0 ? r0.x : j == 1 ? r0.y : j == 2 ? r0.z : r0.w;
                    uint32_t w1 = j == 0 ? r1.x : j == 1 ? r1.y : j == 2 ? r1.z : r1.w;
                    uint32_t w2 = j == 0 ? r2.x : j == 1 ? r2.y : j == 2 ? r2.z : r2.w;
                    uint32_t w3 = j == 0 ? r3.x : j == 1 ? r3.y : j == 2 ? r3.z : r3.w;
                    bool sel = sp >= 32u;
                    uint32_t a  = sel ? w1 : w0;
                    uint32_t bm = sel ? w2 : w1;
                    uint32_t b2 = sel ? w3 : w2;
                    wl[4 + j] = funnel32(bm, a, sp);
                    wh[4 + j] = funnel32(b2, bm, sp);
                }
            }
            LADDER(wl, accL, wq)
            LADDER(wh, accH, wq)
        }
        // ---- relay: wait for token ----
        while (__builtin_amdgcn_readfirstlane(*(volatile int*)&flag) != p)
            __builtin_amdgcn_s_sleep(1);
        float v  = st_v[lane];
        float rf = st_rf[lane];
        // ---- LIF fast path over 64 steps (exact detection of slow-path need) ----
        float vf = v, vmax = -1.0f;
        #pragma unroll
        for (int k = 0; k < 32; ++k) {
            float sc = ((k & 3) == 0) ? SC0 : ((k & 3) == 1) ? SC1 : ((k & 3) == 2) ? SC2 : SC3;
            float I = (float)accL[k] * sc;
            vf = vf + 0.1f * (I - vf);
            vmax = fmaxf(vmax, vf);
        }
        #pragma unroll
        for (int k = 0; k < 32; ++k) {
            float sc = ((k & 3) == 0) ? SC0 : ((k & 3) == 1) ? SC1 : ((k & 3) == 2) ? SC2 : SC3;
            float I = (float)accH[k] * sc;
            vf = vf + 0.1f * (I - vf);
            vmax = fmaxf(vmax, vf);
        }
        bool slow = (rf > 0.0f) || (vmax >= 1.0f);
        if (__ballot(slow) != 0ULL) {
            // ---- exact path (rare: >=7 sigma margin) ----
            float sacc[KSLOT];
            #pragma unroll
            for (int k = 0; k < KSLOT; ++k) sacc[k] = st_sacc[k][lane];
            #pragma unroll
            for (int kk = 0; kk < 64; ++kk) {
                int k = kk & 31;
                float sc = ((k & 3) == 0) ? SC0 : ((k & 3) == 1) ? SC1 : ((k & 3) == 2) ? SC2 : SC3;
                float I = (float)((kk < 32) ? accL[k] : accH[k]) * sc;
                int t = t0 + kk;
                bool active = (rf <= 0.0f);
                float vupd = v + 0.1f * (I - v);
                float vn = active ? vupd : v;
                bool spike = active && (vn >= 1.0f);
                unsigned long long bal = __ballot(spike);
                if (bal != 0ULL) {
                    if (spike) {
                        vn = 0.0f;                // V_RESET
                        #pragma unroll
                        for (int k2 = 0; k2 < KSLOT; ++k2)
                            if (t >= st_[k2] && t < en_[k2]) sacc[k2] += 1.0f;
                    }
                    rf = spike ? 2.0f : fmaxf(rf - 1.0f, 0.0f);
                    if (lane == 0) atomicAdd(&out[B_DIM * KSLOT + t], (float)__popcll(bal));
                } else {
                    rf = fmaxf(rf - 1.0f, 0.0f);
                }
                v = vn;
            }
            #pragma unroll
            for (int k = 0; k < KSLOT; ++k) st_sacc[k][lane] = sacc[k];
        } else {
            v = vf;
            rf = 0.0f;
        }
        st_v[lane]  = v;
        st_rf[lane] = rf;
        __threadfence_block();                     // drain LDS writes before flag release
        if (lane == 0) *(volatile int*)&flag = p + 1;
    }
    // ---- epilogue: after pair 15's relay write, LDS sacc is final ----
    if (sub == WAVES - 1) {
        float wr = w_ro[hbase + lane];
        #pragma unroll
        for (int k = 0; k < KSLOT; ++k) {
            float val = st_sacc[k][lane] * wr;
            #pragma unroll
            for (int o = 32; o > 0; o >>= 1) val += __shfl_down(val, o);
            if (lane == 0) atomicAdd(&out[b * KSLOT + k], val);
        }
    }
}

extern "C" void kernel_launch(void* const* d_in, const int* in_sizes, int n_in,
                              void* d_out, int out_size, void* d_ws, size_t ws_size,
                              hipStream_t stream) {
    const float* x   = (const float*)d_in[0];
    const float* W   = (const float*)d_in[1];
    const float* drw = (const float*)d_in[2];
    const float* wro = (const float*)d_in[3];
    const float* bro = (const float*)d_in[4];
    const int*   ss  = (const int*)d_in[5];
    const int*   se  = (const int*)d_in[6];
    float* out = (float*)d_out;

    uintptr_t base = (uintptr_t)d_ws;
    size_t off = 0;
    auto take = [&](size_t bytes) {
        size_t o = off;
        off = (off + bytes + 255) & ~(size_t)255;
        return (void*)(base + o);
    };
    uint32_t* xbitsT = (uint32_t*)take((size_t)B_DIM * NWORDS * NIN * 4);
    uint4*    pk4    = (uint4*)take((size_t)NG * NHID * 16);
    (void)ws_size;

    prep_kernel<<<581, 256, 0, stream>>>(x, W, drw, bro, xbitsT, pk4, out);
    fused_kernel<<<512, 512, 0, stream>>>(pk4, xbitsT, out, wro, ss, se);
}

// Round 3
// 149.919 us; speedup vs baseline: 1.0631x; 1.0107x over previous
//
#include <hip/hip_runtime.h>
#include <cstdint>

#define B_DIM 32
#define T_DIM 1024
#define NIN 128
#define NG 16       // i-groups of 8
#define NHID 1024
#define KSLOT 8
#define NWORDS 34   // 2 guard words (64 zero bits) + 32 data words
#define WAVES 8
#define CHUNKS 32
#define PAIRS (CHUNKS / 2)
#define ROUNDS (PAIRS / WAVES)
#define WSCALE 16.0f

// Per-k&3 conversion scales for the mask-ladder (masks 1/2/4/8 give 1x/2x/4x/-8x sums;
// nibble 0x8 is -8 as signed i4, folded into a negative scale). All exact powers of 2.
#define SC0 (1.0f / 16.0f)
#define SC1 (1.0f / 32.0f)
#define SC2 (1.0f / 64.0f)
#define SC3 (-1.0f / 128.0f)

// 8 x i4 MAC in one instruction (v_dot8_i32_i4). Fallback preserves semantics.
__device__ __forceinline__ int dot8acc(uint32_t sel, uint32_t wq, int acc) {
#if __has_builtin(__builtin_amdgcn_sdot8)
    return __builtin_amdgcn_sdot8((int)sel, (int)wq, acc, false);
#else
    #pragma unroll
    for (int m = 0; m < 8; ++m) {
        int s = ((int)((sel >> (4 * m)) & 0xF) << 28) >> 28;   // signed i4
        int q = ((int)((wq  >> (4 * m)) & 0xF) << 28) >> 28;   // signed i4
        acc += s * q;
    }
    return acc;
#endif
}

__device__ __forceinline__ uint32_t permb(uint32_t hi, uint32_t lo, uint32_t sel) {
#if __has_builtin(__builtin_amdgcn_perm)
    return __builtin_amdgcn_perm(hi, lo, sel);   // S0=hi(bytes 7..4), S1=lo(bytes 3..0)
#else
    union { uint32_t w[2]; unsigned char b[8]; } src;
    src.w[0] = lo; src.w[1] = hi;
    uint32_t r = 0;
    for (int n = 0; n < 4; ++n) r |= (uint32_t)src.b[(sel >> (8 * n)) & 7] << (8 * n);
    return r;
#endif
}

__device__ __forceinline__ uint32_t funnel32(uint32_t hi, uint32_t lo, uint32_t sh) {
#if __has_builtin(__builtin_amdgcn_alignbit)
    return __builtin_amdgcn_alignbit(hi, lo, sh);   // ((hi:lo) >> (sh&31)) low 32
#else
    return (uint32_t)(((((uint64_t)hi) << 32) | lo) >> (sh & 31));
#endif
}

// ---------------- merged prep kernel ----------------
// blocks   0..511: pack spike bits TRANSPOSED: xbitsT[b][w][i]
// blocks 512..575: packed per-(g,h) params: {sp bytes lo, sp bytes hi, wq nibbles, pad}
//                  (sp = 63 - delay; wq nibble order [0,4,1,5,2,6,3,7])
// blocks 576..580: init out (logits = bias, totals = 0)
__global__ void prep_kernel(const float* __restrict__ x, const float* __restrict__ W,
                            const float* __restrict__ draw, const float* __restrict__ b_ro,
                            uint32_t* __restrict__ xbitsT, uint4* __restrict__ pk4,
                            float* __restrict__ out) {
    int blk = blockIdx.x, tid = threadIdx.x;
    if (blk < 512) {
        int idx = blk * 256 + tid;        // 131072 = b*4096 + w*128 + i
        int b = idx >> 12, w = (idx >> 7) & 31, i = idx & 127;
        const float* xp = x + (size_t)b * T_DIM * NIN + (size_t)w * 32 * NIN + i;
        uint32_t word = 0;
        #pragma unroll
        for (int bit = 0; bit < 32; ++bit) {
            float xv = xp[(size_t)bit * NIN];   // lanes = consecutive i -> coalesced
            word |= (xv != 0.0f) ? (1u << bit) : 0u;
        }
        uint32_t* bp = xbitsT + (size_t)b * NWORDS * NIN;
        bp[(2 + w) * NIN + i] = word;           // transposed: [w][i]
        if (w == 0) { bp[i] = 0u; bp[NIN + i] = 0u; }   // guard rows
    } else if (blk < 576) {
        int idx = (blk - 512) * 256 + tid;    // 16384 = g*1024 + h
        int g = idx >> 10, h = idx & 1023;
        const float* Wp = W    + (size_t)h * NIN + 8 * g;
        const float* Rp = draw + (size_t)h * NIN + 8 * g;
        uint32_t s0 = 0, s1 = 0, wq = 0;
        const int ordm[8] = {0, 4, 1, 5, 2, 6, 3, 7};
        #pragma unroll
        for (int j = 0; j < 4; ++j) {
            int sp_a = 63 - (int)rintf(50.0f / (1.0f + expf(-Rp[j])));      // RNE = jnp.round
            int sp_b = 63 - (int)rintf(50.0f / (1.0f + expf(-Rp[4 + j])));
            s0 |= (uint32_t)sp_a << (8 * j);
            s1 |= (uint32_t)sp_b << (8 * j);
        }
        #pragma unroll
        for (int m = 0; m < 8; ++m) {
            int q = (int)rintf(fminf(fmaxf(Wp[ordm[m]] * WSCALE, -8.0f), 7.0f));
            wq |= ((uint32_t)q & 0xFu) << (4 * m);
        }
        pk4[(size_t)g * NHID + h] = make_uint4(s0, s1, wq, 0u);
    } else {
        int idx = (blk - 576) * 256 + tid;    // 1280 outputs
        if (idx < B_DIM * KSLOT) out[idx] = b_ro[0];
        else if (idx < B_DIM * KSLOT + T_DIM) out[idx] = 0.0f;
    }
}

// mask-ladder: 8 windows (one 32-t word per stream) -> 32 per-t dots via sdot8.
// W_: uint32_t[8] windows; ACC: int[32]; WQ: packed weight nibbles.
#define LADDER(W_, ACC, WQ)                                                     \
    {                                                                           \
        uint32_t A0 = permb(W_[1], W_[0], 0x05010400u);                         \
        uint32_t B0 = permb(W_[1], W_[0], 0x07030602u);                         \
        uint32_t C0 = permb(W_[3], W_[2], 0x05010400u);                         \
        uint32_t D0 = permb(W_[3], W_[2], 0x07030602u);                         \
        uint32_t A1 = permb(W_[5], W_[4], 0x05010400u);                         \
        uint32_t B1 = permb(W_[5], W_[4], 0x07030602u);                         \
        uint32_t C1 = permb(W_[7], W_[6], 0x05010400u);                         \
        uint32_t D1 = permb(W_[7], W_[6], 0x07030602u);                         \
        {                                                                       \
            uint32_t P = permb(C0, A0, 0x05040100u);                            \
            uint32_t Q = permb(C1, A1, 0x05040100u);                            \
            uint32_t X0 = (P & 0x0F0F0F0Fu) | ((Q << 4) & 0xF0F0F0F0u);         \
            uint32_t X1 = ((P >> 4) & 0x0F0F0F0Fu) | (Q & 0xF0F0F0F0u);         \
            ACC[0] = dot8acc(X0 & 0x11111111u, WQ, ACC[0]);                     \
            ACC[1] = dot8acc(X0 & 0x22222222u, WQ, ACC[1]);                     \
            ACC[2] = dot8acc(X0 & 0x44444444u, WQ, ACC[2]);                     \
            ACC[3] = dot8acc(X0 & 0x88888888u, WQ, ACC[3]);                     \
            ACC[4] = dot8acc(X1 & 0x11111111u, WQ, ACC[4]);                     \
            ACC[5] = dot8acc(X1 & 0x22222222u, WQ, ACC[5]);                     \
            ACC[6] = dot8acc(X1 & 0x44444444u, WQ, ACC[6]);                     \
            ACC[7] = dot8acc(X1 & 0x88888888u, WQ, ACC[7]);                     \
        }                                                                       \
        {                                                                       \
            uint32_t P = permb(C0, A0, 0x07060302u);                            \
            uint32_t Q = permb(C1, A1, 0x07060302u);                            \
            uint32_t X2 = (P & 0x0F0F0F0Fu) | ((Q << 4) & 0xF0F0F0F0u);         \
            uint32_t X3 = ((P >> 4) & 0x0F0F0F0Fu) | (Q & 0xF0F0F0F0u);         \
            ACC[8]  = dot8acc(X2 & 0x11111111u, WQ, ACC[8]);                    \
            ACC[9]  = dot8acc(X2 & 0x22222222u, WQ, ACC[9]);                    \
            ACC[10] = dot8acc(X2 & 0x44444444u, WQ, ACC[10]);                   \
            ACC[11] = dot8acc(X2 & 0x88888888u, WQ, ACC[11]);                   \
            ACC[12] = dot8acc(X3 & 0x11111111u, WQ, ACC[12]);                   \
            ACC[13] = dot8acc(X3 & 0x22222222u, WQ, ACC[13]);                   \
            ACC[14] = dot8acc(X3 & 0x44444444u, WQ, ACC[14]);                   \
            ACC[15] = dot8acc(X3 & 0x88888888u, WQ, ACC[15]);                   \
        }                                                                       \
        {                                                                       \
            uint32_t P = permb(D0, B0, 0x05040100u);                            \
            uint32_t Q = permb(D1, B1, 0x05040100u);                            \
            uint32_t X4 = (P & 0x0F0F0F0Fu) | ((Q << 4) & 0xF0F0F0F0u);         \
            uint32_t X5 = ((P >> 4) & 0x0F0F0F0Fu) | (Q & 0xF0F0F0F0u);         \
            ACC[16] = dot8acc(X4 & 0x11111111u, WQ, ACC[16]);                   \
            ACC[17] = dot8acc(X4 & 0x22222222u, WQ, ACC[17]);                   \
            ACC[18] = dot8acc(X4 & 0x44444444u, WQ, ACC[18]);                   \
            ACC[19] = dot8acc(X4 & 0x88888888u, WQ, ACC[19]);                   \
            ACC[20] = dot8acc(X5 & 0x11111111u, WQ, ACC[20]);                   \
            ACC[21] = dot8acc(X5 & 0x22222222u, WQ, ACC[21]);                   \
            ACC[22] = dot8acc(X5 & 0x44444444u, WQ, ACC[22]);                   \
            ACC[23] = dot8acc(X5 & 0x88888888u, WQ, ACC[23]);                   \
        }                                                                       \
        {                                                                       \
            uint32_t P = permb(D0, B0, 0x07060302u);                            \
            uint32_t Q = permb(D1, B1, 0x07060302u);                            \
            uint32_t X6 = (P & 0x0F0F0F0Fu) | ((Q << 4) & 0xF0F0F0F0u);         \
            uint32_t X7 = ((P >> 4) & 0x0F0F0F0Fu) | (Q & 0xF0F0F0F0u);         \
            ACC[24] = dot8acc(X6 & 0x11111111u, WQ, ACC[24]);                   \
            ACC[25] = dot8acc(X6 & 0x22222222u, WQ, ACC[25]);                   \
            ACC[26] = dot8acc(X6 & 0x44444444u, WQ, ACC[26]);                   \
            ACC[27] = dot8acc(X6 & 0x88888888u, WQ, ACC[27]);                   \
            ACC[28] = dot8acc(X7 & 0x11111111u, WQ, ACC[28]);                   \
            ACC[29] = dot8acc(X7 & 0x22222222u, WQ, ACC[29]);                   \
            ACC[30] = dot8acc(X7 & 0x44444444u, WQ, ACC[30]);                   \
            ACC[31] = dot8acc(X7 & 0x88888888u, WQ, ACC[31]);                   \
        }                                                                       \
    }

// build both pair-windows for 4 streams from 4 row-quads + packed sp byte word
#define BUILD4(SPW, R0, R1, R2, R3, WL, WH, BASE)                               \
    {                                                                           \
        uint32_t sp0 = (SPW) & 0xFFu;                                           \
        uint32_t sp1 = ((SPW) >> 8) & 0xFFu;                                    \
        uint32_t sp2 = ((SPW) >> 16) & 0xFFu;                                   \
        uint32_t sp3 = (SPW) >> 24;                                             \
        bool se0 = sp0 >= 32u, se1 = sp1 >= 32u, se2 = sp2 >= 32u, se3 = sp3 >= 32u; \
        uint32_t a0 = se0 ? R1.x : R0.x, m0 = se0 ? R2.x : R1.x, c0 = se0 ? R3.x : R2.x; \
        uint32_t a1 = se1 ? R1.y : R0.y, m1 = se1 ? R2.y : R1.y, c1 = se1 ? R3.y : R2.y; \
        uint32_t a2 = se2 ? R1.z : R0.z, m2 = se2 ? R2.z : R1.z, c2 = se2 ? R3.z : R2.z; \
        uint32_t a3 = se3 ? R1.w : R0.w, m3 = se3 ? R2.w : R1.w, c3 = se3 ? R3.w : R2.w; \
        WL[BASE + 0] = funnel32(m0, a0, sp0); WH[BASE + 0] = funnel32(c0, m0, sp0); \
        WL[BASE + 1] = funnel32(m1, a1, sp1); WH[BASE + 1] = funnel32(c1, m1, sp1); \
        WL[BASE + 2] = funnel32(m2, a2, sp2); WH[BASE + 2] = funnel32(c2, m2, sp2); \
        WL[BASE + 3] = funnel32(m3, a3, sp3); WH[BASE + 3] = funnel32(c3, m3, sp3); \
    }

// ---------------- fused sdot8 mask-ladder + wave-relay LIF ----------------
// block = (b, hg of 64 h), 512 threads = 8 waves, grid 512.
// R16 = R15 (pair fusion, 82 us) + explicit 1-deep software pipeline on the
// g-loop. Rationale: VALUBusy 73% with 0 bank conflicts and occupancy that
// R14 proved irrelevant -> the ~27% idle is LDS latency exposed at each
// g-iteration top (9 ds_reads consumed immediately; unroll-1 blocks
// cross-iteration overlap). Rotation: build windows from LAST iteration's row
// regs, then issue g+1's ds_reads (branchless wrap (g+1)&15), then run the two
// LADDERs (~224 VALU) over the in-flight loads.
// Register audit: acc 64 + rows 32 + pkc 4 + wl/wh 16 + addr ~6 = ~122 < 128
// cap from launch_bounds(512,4). Spill tripwire: WRITE_SIZE >> 128 KB.
__global__ __launch_bounds__(512, 4) void fused_kernel(
    const uint4* __restrict__ pk4, const uint32_t* __restrict__ xbitsT,
    float* __restrict__ out, const float* __restrict__ w_ro,
    const int* __restrict__ ss, const int* __restrict__ se) {
    __shared__ uint32_t lds_x[NWORDS * NIN];  // [w][i]   17 KB (transposed)
    __shared__ uint4    lds_pk[NG * 64];      // [g][hl]  16 KB {sp lo, sp hi, wq, pad}
    __shared__ float st_v[64];
    __shared__ float st_rf[64];
    __shared__ float st_sacc[KSLOT][64];      // authoritative (lazy relay)
    __shared__ int   flag;

    int bx = blockIdx.x;
    int hg = bx & 15;
    int b  = bx >> 4;
    int tid  = threadIdx.x;
    int lane = tid & 63;
    int sub  = tid >> 6;
    int hbase = hg * 64;

    for (int idx = tid; idx < NWORDS * NIN; idx += 512)
        lds_x[idx] = xbitsT[(size_t)b * NWORDS * NIN + idx];
    for (int idx = tid; idx < NG * 64; idx += 512) {
        int g = idx >> 6, hl = idx & 63;
        lds_pk[idx] = pk4[(size_t)g * NHID + hbase + hl];
    }
    if (tid < 64) { st_v[tid] = 0.0f; st_rf[tid] = 0.0f; }
    if (tid < KSLOT * 64) ((float*)st_sacc)[tid] = 0.0f;
    if (tid == 0) flag = 0;
    __syncthreads();

    int st_[KSLOT], en_[KSLOT];
    #pragma unroll
    for (int k = 0; k < KSLOT; ++k) {
        st_[k] = __builtin_amdgcn_readfirstlane(ss[k]);
        en_[k] = __builtin_amdgcn_readfirstlane(se[k]);
    }

    for (int rl = 0; rl < ROUNDS; ++rl) {
        int p  = __builtin_amdgcn_readfirstlane(rl * WAVES + sub);   // pair index 0..15
        int t0 = p * 64;
        int accL[32], accH[32];
        #pragma unroll
        for (int k = 0; k < 32; ++k) { accL[k] = 0; accH[k] = 0; }
        const uint32_t* xrow = lds_x + (2 * p) * NIN;   // rows 2p .. 2p+3 used

        // prologue: load g=0 rows + params
        uint4 pkc = lds_pk[lane];
        uint4 q0 = *(const uint4*)(xrow);
        uint4 q1 = *(const uint4*)(xrow + NIN);
        uint4 q2 = *(const uint4*)(xrow + 2 * NIN);
        uint4 q3 = *(const uint4*)(xrow + 3 * NIN);
        uint4 q4 = *(const uint4*)(xrow + 4);
        uint4 q5 = *(const uint4*)(xrow + NIN + 4);
        uint4 q6 = *(const uint4*)(xrow + 2 * NIN + 4);
        uint4 q7 = *(const uint4*)(xrow + 3 * NIN + 4);

        #pragma unroll 1
        for (int g = 0; g < NG; ++g) {
            // ---- consume current regs into windows (rows die here) ----
            uint32_t wq = pkc.z;
            uint32_t wl[8], wh[8];
            BUILD4(pkc.x, q0, q1, q2, q3, wl, wh, 0)
            BUILD4(pkc.y, q4, q5, q6, q7, wl, wh, 4)
            // ---- prefetch next g (branchless wrap; final extra loads harmless) ----
            {
                int gn = (g + 1) & 15;
                pkc = lds_pk[(gn << 6) | lane];
                const uint32_t* xr = xrow + 8 * gn;
                q0 = *(const uint4*)(xr);
                q1 = *(const uint4*)(xr + NIN);
                q2 = *(const uint4*)(xr + 2 * NIN);
                q3 = *(const uint4*)(xr + 3 * NIN);
                q4 = *(const uint4*)(xr + 4);
                q5 = *(const uint4*)(xr + NIN + 4);
                q6 = *(const uint4*)(xr + 2 * NIN + 4);
                q7 = *(const uint4*)(xr + 3 * NIN + 4);
            }
            // ---- heavy VALU block covers the in-flight ds_reads ----
            LADDER(wl, accL, wq)
            LADDER(wh, accH, wq)
        }
        // ---- relay: wait for token ----
        while (__builtin_amdgcn_readfirstlane(*(volatile int*)&flag) != p)
            __builtin_amdgcn_s_sleep(1);
        float v  = st_v[lane];
        float rf = st_rf[lane];
        // ---- LIF fast path over 64 steps (exact detection of slow-path need) ----
        float vf = v, vmax = -1.0f;
        #pragma unroll
        for (int k = 0; k < 32; ++k) {
            float sc = ((k & 3) == 0) ? SC0 : ((k & 3) == 1) ? SC1 : ((k & 3) == 2) ? SC2 : SC3;
            float I = (float)accL[k] * sc;
            vf = vf + 0.1f * (I - vf);
            vmax = fmaxf(vmax, vf);
        }
        #pragma unroll
        for (int k = 0; k < 32; ++k) {
            float sc = ((k & 3) == 0) ? SC0 : ((k & 3) == 1) ? SC1 : ((k & 3) == 2) ? SC2 : SC3;
            float I = (float)accH[k] * sc;
            vf = vf + 0.1f * (I - vf);
            vmax = fmaxf(vmax, vf);
        }
        bool slow = (rf > 0.0f) || (vmax >= 1.0f);
        if (__ballot(slow) != 0ULL) {
            // ---- exact path (rare: >=7 sigma margin) ----
            float sacc[KSLOT];
            #pragma unroll
            for (int k = 0; k < KSLOT; ++k) sacc[k] = st_sacc[k][lane];
            #pragma unroll
            for (int kk = 0; kk < 64; ++kk) {
                int k = kk & 31;
                float sc = ((k & 3) == 0) ? SC0 : ((k & 3) == 1) ? SC1 : ((k & 3) == 2) ? SC2 : SC3;
                float I = (float)((kk < 32) ? accL[k] : accH[k]) * sc;
                int t = t0 + kk;
                bool active = (rf <= 0.0f);
                float vupd = v + 0.1f * (I - v);
                float vn = active ? vupd : v;
                bool spike = active && (vn >= 1.0f);
                unsigned long long bal = __ballot(spike);
                if (bal != 0ULL) {
                    if (spike) {
                        vn = 0.0f;                // V_RESET
                        #pragma unroll
                        for (int k2 = 0; k2 < KSLOT; ++k2)
                            if (t >= st_[k2] && t < en_[k2]) sacc[k2] += 1.0f;
                    }
                    rf = spike ? 2.0f : fmaxf(rf - 1.0f, 0.0f);
                    if (lane == 0) atomicAdd(&out[B_DIM * KSLOT + t], (float)__popcll(bal));
                } else {
                    rf = fmaxf(rf - 1.0f, 0.0f);
                }
                v = vn;
            }
            #pragma unroll
            for (int k = 0; k < KSLOT; ++k) st_sacc[k][lane] = sacc[k];
        } else {
            v = vf;
            rf = 0.0f;
        }
        st_v[lane]  = v;
        st_rf[lane] = rf;
        __threadfence_block();                     // drain LDS writes before flag release
        if (lane == 0) *(volatile int*)&flag = p + 1;
    }
    // ---- epilogue: after pair 15's relay write, LDS sacc is final ----
    if (sub == WAVES - 1) {
        float wr = w_ro[hbase + lane];
        #pragma unroll
        for (int k = 0; k < KSLOT; ++k) {
            float val = st_sacc[k][lane] * wr;
            #pragma unroll
            for (int o = 32; o > 0; o >>= 1) val += __shfl_down(val, o);
            if (lane == 0) atomicAdd(&out[b * KSLOT + k], val);
        }
    }
}

extern "C" void kernel_launch(void* const* d_in, const int* in_sizes, int n_in,
                              void* d_out, int out_size, void* d_ws, size_t ws_size,
                              hipStream_t stream) {
    const float* x   = (const float*)d_in[0];
    const float* W   = (const float*)d_in[1];
    const float* drw = (const float*)d_in[2];
    const float* wro = (const float*)d_in[3];
    const float* bro = (const float*)d_in[4];
    const int*   ss  = (const int*)d_in[5];
    const int*   se  = (const int*)d_in[6];
    float* out = (float*)d_out;

    uintptr_t base = (uintptr_t)d_ws;
    size_t off = 0;
    auto take = [&](size_t bytes) {
        size_t o = off;
        off = (off + bytes + 255) & ~(size_t)255;
        return (void*)(base + o);
    };
    uint32_t* xbitsT = (uint32_t*)take((size_t)B_DIM * NWORDS * NIN * 4);
    uint4*    pk4    = (uint4*)take((size_t)NG * NHID * 16);
    (void)ws_size;

    prep_kernel<<<581, 256, 0, stream>>>(x, W, drw, bro, xbitsT, pk4, out);
    fused_kernel<<<512, 512, 0, stream>>>(pk4, xbitsT, out, wro, ss, se);
}

// Round 4
// 149.254 us; speedup vs baseline: 1.0678x; 1.0045x over previous
//
#include <hip/hip_runtime.h>
#include <cstdint>

#define B_DIM 32
#define T_DIM 1024
#define NIN 128
#define NG 16       // i-groups of 8
#define NHID 1024
#define KSLOT 8
#define NWORDS 34   // 2 guard words (64 zero bits) + 32 data words
#define WAVES 8
#define CHUNKS 32
#define PAIRS (CHUNKS / 2)
#define ROUNDS (PAIRS / WAVES)
#define WSCALE 16.0f

// Incremental-mask ladder (R17): prefix masks {0x11,0x33,0x77,none} instead of
// {0x11,0x22,0x44,0x88}. acc[4q+j] = prefix sums; per-t currents recovered by
// integer differencing at LIF time (bit-exact: diffs reproduce the identical
// integers the old bit-plane accumulators held). The unmasked dot8's nibble
// bit3 contributes -8 (signed i4), folded into SC3's sign exactly as before.
#define SC0 (1.0f / 16.0f)
#define SC1 (1.0f / 32.0f)
#define SC2 (1.0f / 64.0f)
#define SC3 (-1.0f / 128.0f)

// 8 x i4 MAC in one instruction (v_dot8_i32_i4). Fallback preserves semantics.
__device__ __forceinline__ int dot8acc(uint32_t sel, uint32_t wq, int acc) {
#if __has_builtin(__builtin_amdgcn_sdot8)
    return __builtin_amdgcn_sdot8((int)sel, (int)wq, acc, false);
#else
    #pragma unroll
    for (int m = 0; m < 8; ++m) {
        int s = ((int)((sel >> (4 * m)) & 0xF) << 28) >> 28;   // signed i4
        int q = ((int)((wq  >> (4 * m)) & 0xF) << 28) >> 28;   // signed i4
        acc += s * q;
    }
    return acc;
#endif
}

__device__ __forceinline__ uint32_t permb(uint32_t hi, uint32_t lo, uint32_t sel) {
#if __has_builtin(__builtin_amdgcn_perm)
    return __builtin_amdgcn_perm(hi, lo, sel);   // S0=hi(bytes 7..4), S1=lo(bytes 3..0)
#else
    union { uint32_t w[2]; unsigned char b[8]; } src;
    src.w[0] = lo; src.w[1] = hi;
    uint32_t r = 0;
    for (int n = 0; n < 4; ++n) r |= (uint32_t)src.b[(sel >> (8 * n)) & 7] << (8 * n);
    return r;
#endif
}

__device__ __forceinline__ uint32_t funnel32(uint32_t hi, uint32_t lo, uint32_t sh) {
#if __has_builtin(__builtin_amdgcn_alignbit)
    return __builtin_amdgcn_alignbit(hi, lo, sh);   // ((hi:lo) >> (sh&31)) low 32
#else
    return (uint32_t)(((((uint64_t)hi) << 32) | lo) >> (sh & 31));
#endif
}

// ---------------- merged prep kernel ----------------
// blocks   0..511: pack spike bits TRANSPOSED: xbitsT[b][w][i]
// blocks 512..575: packed per-(g,h) params: {sp bytes lo, sp bytes hi, wq nibbles, pad}
//                  (sp = 63 - delay; wq nibble order [0,4,1,5,2,6,3,7])
// blocks 576..580: init out (logits = bias, totals = 0)
__global__ void prep_kernel(const float* __restrict__ x, const float* __restrict__ W,
                            const float* __restrict__ draw, const float* __restrict__ b_ro,
                            uint32_t* __restrict__ xbitsT, uint4* __restrict__ pk4,
                            float* __restrict__ out) {
    int blk = blockIdx.x, tid = threadIdx.x;
    if (blk < 512) {
        int idx = blk * 256 + tid;        // 131072 = b*4096 + w*128 + i
        int b = idx >> 12, w = (idx >> 7) & 31, i = idx & 127;
        const float* xp = x + (size_t)b * T_DIM * NIN + (size_t)w * 32 * NIN + i;
        uint32_t word = 0;
        #pragma unroll
        for (int bit = 0; bit < 32; ++bit) {
            float xv = xp[(size_t)bit * NIN];   // lanes = consecutive i -> coalesced
            word |= (xv != 0.0f) ? (1u << bit) : 0u;
        }
        uint32_t* bp = xbitsT + (size_t)b * NWORDS * NIN;
        bp[(2 + w) * NIN + i] = word;           // transposed: [w][i]
        if (w == 0) { bp[i] = 0u; bp[NIN + i] = 0u; }   // guard rows
    } else if (blk < 576) {
        int idx = (blk - 512) * 256 + tid;    // 16384 = g*1024 + h
        int g = idx >> 10, h = idx & 1023;
        const float* Wp = W    + (size_t)h * NIN + 8 * g;
        const float* Rp = draw + (size_t)h * NIN + 8 * g;
        uint32_t s0 = 0, s1 = 0, wq = 0;
        const int ordm[8] = {0, 4, 1, 5, 2, 6, 3, 7};
        #pragma unroll
        for (int j = 0; j < 4; ++j) {
            int sp_a = 63 - (int)rintf(50.0f / (1.0f + expf(-Rp[j])));      // RNE = jnp.round
            int sp_b = 63 - (int)rintf(50.0f / (1.0f + expf(-Rp[4 + j])));
            s0 |= (uint32_t)sp_a << (8 * j);
            s1 |= (uint32_t)sp_b << (8 * j);
        }
        #pragma unroll
        for (int m = 0; m < 8; ++m) {
            int q = (int)rintf(fminf(fmaxf(Wp[ordm[m]] * WSCALE, -8.0f), 7.0f));
            wq |= ((uint32_t)q & 0xFu) << (4 * m);
        }
        pk4[(size_t)g * NHID + h] = make_uint4(s0, s1, wq, 0u);
    } else {
        int idx = (blk - 576) * 256 + tid;    // 1280 outputs
        if (idx < B_DIM * KSLOT) out[idx] = b_ro[0];
        else if (idx < B_DIM * KSLOT + T_DIM) out[idx] = 0.0f;
    }
}

// prefix-mask quad: 3 ands + 4 dots (was 4 ands + 4 dots)
#define QUAD4(X, ACC, BASE, WQ)                                                 \
    ACC[(BASE)+0] = dot8acc((X) & 0x11111111u, WQ, ACC[(BASE)+0]);              \
    ACC[(BASE)+1] = dot8acc((X) & 0x33333333u, WQ, ACC[(BASE)+1]);              \
    ACC[(BASE)+2] = dot8acc((X) & 0x77777777u, WQ, ACC[(BASE)+2]);              \
    ACC[(BASE)+3] = dot8acc((X),               WQ, ACC[(BASE)+3]);

// mask-ladder: 8 windows (one 32-t word per stream) -> 32 prefix dots via sdot8.
// X-mix expressions kept in ((a&M)|(b&~M)) form for v_bfi_b32 pattern-match.
#define LADDER(W_, ACC, WQ)                                                     \
    {                                                                           \
        uint32_t A0 = permb(W_[1], W_[0], 0x05010400u);                         \
        uint32_t B0 = permb(W_[1], W_[0], 0x07030602u);                         \
        uint32_t C0 = permb(W_[3], W_[2], 0x05010400u);                         \
        uint32_t D0 = permb(W_[3], W_[2], 0x07030602u);                         \
        uint32_t A1 = permb(W_[5], W_[4], 0x05010400u);                         \
        uint32_t B1 = permb(W_[5], W_[4], 0x07030602u);                         \
        uint32_t C1 = permb(W_[7], W_[6], 0x05010400u);                         \
        uint32_t D1 = permb(W_[7], W_[6], 0x07030602u);                         \
        {                                                                       \
            uint32_t P = permb(C0, A0, 0x05040100u);                            \
            uint32_t Q = permb(C1, A1, 0x05040100u);                            \
            uint32_t X0 = (P & 0x0F0F0F0Fu) | ((Q << 4) & 0xF0F0F0F0u);         \
            uint32_t X1 = ((P >> 4) & 0x0F0F0F0Fu) | (Q & 0xF0F0F0F0u);         \
            QUAD4(X0, ACC, 0, WQ)                                               \
            QUAD4(X1, ACC, 4, WQ)                                               \
        }                                                                       \
        {                                                                       \
            uint32_t P = permb(C0, A0, 0x07060302u);                            \
            uint32_t Q = permb(C1, A1, 0x07060302u);                            \
            uint32_t X2 = (P & 0x0F0F0F0Fu) | ((Q << 4) & 0xF0F0F0F0u);         \
            uint32_t X3 = ((P >> 4) & 0x0F0F0F0Fu) | (Q & 0xF0F0F0F0u);         \
            QUAD4(X2, ACC, 8, WQ)                                               \
            QUAD4(X3, ACC, 12, WQ)                                              \
        }                                                                       \
        {                                                                       \
            uint32_t P = permb(D0, B0, 0x05040100u);                            \
            uint32_t Q = permb(D1, B1, 0x05040100u);                            \
            uint32_t X4 = (P & 0x0F0F0F0Fu) | ((Q << 4) & 0xF0F0F0F0u);         \
            uint32_t X5 = ((P >> 4) & 0x0F0F0F0Fu) | (Q & 0xF0F0F0F0u);         \
            QUAD4(X4, ACC, 16, WQ)                                              \
            QUAD4(X5, ACC, 20, WQ)                                              \
        }                                                                       \
        {                                                                       \
            uint32_t P = permb(D0, B0, 0x07060302u);                            \
            uint32_t Q = permb(D1, B1, 0x07060302u);                            \
            uint32_t X6 = (P & 0x0F0F0F0Fu) | ((Q << 4) & 0xF0F0F0F0u);         \
            uint32_t X7 = ((P >> 4) & 0x0F0F0F0Fu) | (Q & 0xF0F0F0F0u);         \
            QUAD4(X6, ACC, 24, WQ)                                              \
            QUAD4(X7, ACC, 28, WQ)                                              \
        }                                                                       \
    }

// build both pair-windows for 4 streams from 4 row-quads + packed sp byte word
#define BUILD4(SPW, R0, R1, R2, R3, WL, WH, BASE)                               \
    {                                                                           \
        uint32_t sp0 = (SPW) & 0xFFu;                                           \
        uint32_t sp1 = ((SPW) >> 8) & 0xFFu;                                    \
        uint32_t sp2 = ((SPW) >> 16) & 0xFFu;                                   \
        uint32_t sp3 = (SPW) >> 24;                                             \
        bool se0 = sp0 >= 32u, se1 = sp1 >= 32u, se2 = sp2 >= 32u, se3 = sp3 >= 32u; \
        uint32_t a0 = se0 ? R1.x : R0.x, m0 = se0 ? R2.x : R1.x, c0 = se0 ? R3.x : R2.x; \
        uint32_t a1 = se1 ? R1.y : R0.y, m1 = se1 ? R2.y : R1.y, c1 = se1 ? R3.y : R2.y; \
        uint32_t a2 = se2 ? R1.z : R0.z, m2 = se2 ? R2.z : R1.z, c2 = se2 ? R3.z : R2.z; \
        uint32_t a3 = se3 ? R1.w : R0.w, m3 = se3 ? R2.w : R1.w, c3 = se3 ? R3.w : R2.w; \
        WL[BASE + 0] = funnel32(m0, a0, sp0); WH[BASE + 0] = funnel32(c0, m0, sp0); \
        WL[BASE + 1] = funnel32(m1, a1, sp1); WH[BASE + 1] = funnel32(c1, m1, sp1); \
        WL[BASE + 2] = funnel32(m2, a2, sp2); WH[BASE + 2] = funnel32(c2, m2, sp2); \
        WL[BASE + 3] = funnel32(m3, a3, sp3); WH[BASE + 3] = funnel32(c3, m3, sp3); \
    }

// fast-path LIF over one 32-acc half with prefix-diff current recovery.
// I values bit-exact vs old bit-plane accs: a1-a0 == old 2*A1 etc.
#define FAST32(A)                                                               \
    _Pragma("unroll")                                                           \
    for (int q = 0; q < 8; ++q) {                                               \
        int a0 = A[4*q], a1 = A[4*q+1], a2 = A[4*q+2], a3 = A[4*q+3];           \
        float v0, v1, v2, v3;                                                   \
        vf += 0.1f * ((float)a0        * SC0 - vf); v0 = vf;                    \
        vf += 0.1f * ((float)(a1 - a0) * SC1 - vf); v1 = vf;                    \
        vf += 0.1f * ((float)(a2 - a1) * SC2 - vf); v2 = vf;                    \
        vf += 0.1f * ((float)(a3 - a2) * SC3 - vf); v3 = vf;                    \
        vmax = fmaxf(vmax, fmaxf(fmaxf(v0, v1), fmaxf(v2, v3)));                \
    }

// exact-path LIF over one 32-acc half (rare), same prefix-diff recovery.
#define SLOW32(A, TBASE)                                                        \
    _Pragma("unroll")                                                           \
    for (int q = 0; q < 8; ++q) {                                               \
        int a0 = A[4*q], a1 = A[4*q+1], a2 = A[4*q+2], a3 = A[4*q+3];           \
        _Pragma("unroll")                                                       \
        for (int j = 0; j < 4; ++j) {                                           \
            float I = (j == 0) ? (float)a0        * SC0                         \
                    : (j == 1) ? (float)(a1 - a0) * SC1                         \
                    : (j == 2) ? (float)(a2 - a1) * SC2                         \
                    :            (float)(a3 - a2) * SC3;                        \
            int t = (TBASE) + 4 * q + j;                                        \
            bool active = (rf <= 0.0f);                                         \
            float vupd = v + 0.1f * (I - v);                                    \
            float vn = active ? vupd : v;                                       \
            bool spike = active && (vn >= 1.0f);                                \
            unsigned long long bal = __ballot(spike);                           \
            if (bal != 0ULL) {                                                  \
                if (spike) {                                                    \
                    vn = 0.0f;                /* V_RESET */                     \
                    _Pragma("unroll")                                           \
                    for (int k2 = 0; k2 < KSLOT; ++k2)                          \
                        if (t >= st_[k2] && t < en_[k2]) sacc[k2] += 1.0f;      \
                }                                                               \
                rf = spike ? 2.0f : fmaxf(rf - 1.0f, 0.0f);                     \
                if (lane == 0) atomicAdd(&out[B_DIM * KSLOT + t], (float)__popcll(bal)); \
            } else {                                                            \
                rf = fmaxf(rf - 1.0f, 0.0f);                                    \
            }                                                                   \
            v = vn;                                                             \
        }                                                                       \
    }

// ---------------- fused sdot8 mask-ladder + wave-relay LIF ----------------
// block = (b, hg of 64 h), 512 threads = 8 waves, grid 512.
// R17 = R15 (pair fusion, 82 us) + incremental-mask ladder. R16's SW pipeline
// reverted (neutral: TLP at 4 waves/SIMD already hides LDS latency; VALUBusy
// FELL 73.5->71.5). Evidence stack: R14 (2x waves neutral) + R16 (ILP neutral)
// + R15 (-11% inst -> -10% busy time) => issue-bound; static inst count is the
// only paying lever. This round: -16 v_and per g (256/pair) via prefix masks,
// +48 int subs per pair at LIF; max3-fusable vmax chains; quad-static scales.
// R12/R14 lesson: acc[] resident; spill tripwire WRITE_SIZE >> 128 KB.
__global__ __launch_bounds__(512, 4) void fused_kernel(
    const uint4* __restrict__ pk4, const uint32_t* __restrict__ xbitsT,
    float* __restrict__ out, const float* __restrict__ w_ro,
    const int* __restrict__ ss, const int* __restrict__ se) {
    __shared__ uint32_t lds_x[NWORDS * NIN];  // [w][i]   17 KB (transposed)
    __shared__ uint4    lds_pk[NG * 64];      // [g][hl]  16 KB {sp lo, sp hi, wq, pad}
    __shared__ float st_v[64];
    __shared__ float st_rf[64];
    __shared__ float st_sacc[KSLOT][64];      // authoritative (lazy relay)
    __shared__ int   flag;

    int bx = blockIdx.x;
    int hg = bx & 15;
    int b  = bx >> 4;
    int tid  = threadIdx.x;
    int lane = tid & 63;
    int sub  = tid >> 6;
    int hbase = hg * 64;

    for (int idx = tid; idx < NWORDS * NIN; idx += 512)
        lds_x[idx] = xbitsT[(size_t)b * NWORDS * NIN + idx];
    for (int idx = tid; idx < NG * 64; idx += 512) {
        int g = idx >> 6, hl = idx & 63;
        lds_pk[idx] = pk4[(size_t)g * NHID + hbase + hl];
    }
    if (tid < 64) { st_v[tid] = 0.0f; st_rf[tid] = 0.0f; }
    if (tid < KSLOT * 64) ((float*)st_sacc)[tid] = 0.0f;
    if (tid == 0) flag = 0;
    __syncthreads();

    int st_[KSLOT], en_[KSLOT];
    #pragma unroll
    for (int k = 0; k < KSLOT; ++k) {
        st_[k] = __builtin_amdgcn_readfirstlane(ss[k]);
        en_[k] = __builtin_amdgcn_readfirstlane(se[k]);
    }

    for (int rl = 0; rl < ROUNDS; ++rl) {
        int p  = __builtin_amdgcn_readfirstlane(rl * WAVES + sub);   // pair index 0..15
        int t0 = p * 64;
        int accL[32], accH[32];
        #pragma unroll
        for (int k = 0; k < 32; ++k) { accL[k] = 0; accH[k] = 0; }
        const uint32_t* xrow = lds_x + (2 * p) * NIN;   // rows 2p .. 2p+3 used
        #pragma unroll 1
        for (int g = 0; g < NG; ++g) {
            uint4 pkc = lds_pk[(g << 6) | lane];  // one ds_read_b128: {sp lo, sp hi, wq}
            uint32_t wq = pkc.z;
            uint32_t wl[8], wh[8];
            const uint32_t* xr = xrow + 8 * g;
            {   // half 0: streams 8g..8g+3 — 4 uniform b128 rows serve BOTH chunks
                uint4 r0 = *(const uint4*)(xr);
                uint4 r1 = *(const uint4*)(xr + NIN);
                uint4 r2 = *(const uint4*)(xr + 2 * NIN);
                uint4 r3 = *(const uint4*)(xr + 3 * NIN);
                BUILD4(pkc.x, r0, r1, r2, r3, wl, wh, 0)
            }
            {   // half 1: streams 8g+4..8g+7
                uint4 r0 = *(const uint4*)(xr + 4);
                uint4 r1 = *(const uint4*)(xr + NIN + 4);
                uint4 r2 = *(const uint4*)(xr + 2 * NIN + 4);
                uint4 r3 = *(const uint4*)(xr + 3 * NIN + 4);
                BUILD4(pkc.y, r0, r1, r2, r3, wl, wh, 4)
            }
            LADDER(wl, accL, wq)
            LADDER(wh, accH, wq)
        }
        // ---- relay: wait for token ----
        while (__builtin_amdgcn_readfirstlane(*(volatile int*)&flag) != p)
            __builtin_amdgcn_s_sleep(1);
        float v  = st_v[lane];
        float rf = st_rf[lane];
        // ---- LIF fast path over 64 steps (exact detection of slow-path need) ----
        float vf = v, vmax = -1.0f;
        FAST32(accL)
        FAST32(accH)
        bool slow = (rf > 0.0f) || (vmax >= 1.0f);
        if (__ballot(slow) != 0ULL) {
            // ---- exact path (rare: >=7 sigma margin) ----
            float sacc[KSLOT];
            #pragma unroll
            for (int k = 0; k < KSLOT; ++k) sacc[k] = st_sacc[k][lane];
            SLOW32(accL, t0)
            SLOW32(accH, t0 + 32)
            #pragma unroll
            for (int k = 0; k < KSLOT; ++k) st_sacc[k][lane] = sacc[k];
        } else {
            v = vf;
            rf = 0.0f;
        }
        st_v[lane]  = v;
        st_rf[lane] = rf;
        __threadfence_block();                     // drain LDS writes before flag release
        if (lane == 0) *(volatile int*)&flag = p + 1;
    }
    // ---- epilogue: after pair 15's relay write, LDS sacc is final ----
    if (sub == WAVES - 1) {
        float wr = w_ro[hbase + lane];
        #pragma unroll
        for (int k = 0; k < KSLOT; ++k) {
            float val = st_sacc[k][lane] * wr;
            #pragma unroll
            for (int o = 32; o > 0; o >>= 1) val += __shfl_down(val, o);
            if (lane == 0) atomicAdd(&out[b * KSLOT + k], val);
        }
    }
}

extern "C" void kernel_launch(void* const* d_in, const int* in_sizes, int n_in,
                              void* d_out, int out_size, void* d_ws, size_t ws_size,
                              hipStream_t stream) {
    const float* x   = (const float*)d_in[0];
    const float* W   = (const float*)d_in[1];
    const float* drw = (const float*)d_in[2];
    const float* wro = (const float*)d_in[3];
    const float* bro = (const float*)d_in[4];
    const int*   ss  = (const int*)d_in[5];
    const int*   se  = (const int*)d_in[6];
    float* out = (float*)d_out;

    uintptr_t base = (uintptr_t)d_ws;
    size_t off = 0;
    auto take = [&](size_t bytes) {
        size_t o = off;
        off = (off + bytes + 255) & ~(size_t)255;
        return (void*)(base + o);
    };
    uint32_t* xbitsT = (uint32_t*)take((size_t)B_DIM * NWORDS * NIN * 4);
    uint4*    pk4    = (uint4*)take((size_t)NG * NHID * 16);
    (void)ws_size;

    prep_kernel<<<581, 256, 0, stream>>>(x, W, drw, bro, xbitsT, pk4, out);
    fused_kernel<<<512, 512, 0, stream>>>(pk4, xbitsT, out, wro, ss, se);
}